// Round 1
// baseline (324.905 us; speedup 1.0000x reference)
//
#include <hip/hip_runtime.h>
#include <hip/hip_bf16.h>

// Problem constants: S=8192, D_IN=512, D_OUT=64
// causal attention: O = softmax(tril(QK^T)/8) @ V, Q=x@Wq^T etc.

typedef __attribute__((ext_vector_type(8))) short short8;   // 8 bf16 (4 VGPRs) MFMA A/B frag
typedef __attribute__((ext_vector_type(4))) float f32x4;    // MFMA C/D frag

__device__ inline unsigned short f2bf(float f) {
    union { float f; unsigned u; } v; v.f = f;
    unsigned r = (v.u + 0x7FFFu + ((v.u >> 16) & 1u)) >> 16;
    return (unsigned short)r;
}

// ---------------- kernel 0a: cast x (fp32 -> bf16) ----------------
__global__ __launch_bounds__(256) void cast_x_kernel(const float* __restrict__ src,
                                                     unsigned short* __restrict__ dst, int n4) {
    int i = blockIdx.x * blockDim.x + threadIdx.x;
    if (i < n4) {
        float4 v = ((const float4*)src)[i];
        ushort4 o;
        o.x = f2bf(v.x); o.y = f2bf(v.y); o.z = f2bf(v.z); o.w = f2bf(v.w);
        ((ushort4*)dst)[i] = o;
    }
}

// ---------------- kernel 0b: cast the three W matrices ----------------
__global__ __launch_bounds__(256) void cast_w_kernel(const float* __restrict__ wq,
                                                     const float* __restrict__ wk,
                                                     const float* __restrict__ wv,
                                                     unsigned short* __restrict__ dst) {
    const float* src = (blockIdx.y == 0) ? wq : ((blockIdx.y == 1) ? wk : wv);
    int i = blockIdx.x * blockDim.x + threadIdx.x;   // < 8192 (= 32768/4)
    float4 v = ((const float4*)src)[i];
    ushort4 o;
    o.x = f2bf(v.x); o.y = f2bf(v.y); o.z = f2bf(v.z); o.w = f2bf(v.w);
    ((ushort4*)(dst + blockIdx.y * 32768))[i] = o;
}

// ---------------- kernel 1: QKV projection via MFMA ----------------
// One wave per block; 32 rows of x per wave; blockIdx.y selects Q/K/V.
// Writes Q scaled by 1/8 (row-major bf16), K (row-major bf16), V transposed [64][8192] bf16.
__global__ __launch_bounds__(64) void proj_kernel(const unsigned short* __restrict__ xb,
                                                  const unsigned short* __restrict__ wb,
                                                  unsigned short* __restrict__ qb,
                                                  unsigned short* __restrict__ kb,
                                                  unsigned short* __restrict__ vt) {
    const int lane = threadIdx.x;
    const int l16 = lane & 15, quad = lane >> 4;
    const int mat = blockIdx.y;
    const int r0  = blockIdx.x * 32;
    const unsigned short* w = wb + mat * 64 * 512;

    f32x4 acc[2][4] = {};   // [row-group of 16][n-chunk of 16]
#pragma unroll 4
    for (int kc = 0; kc < 16; ++kc) {
        const int kbase = kc * 32 + quad * 8;
        short8 a0 = *(const short8*)(xb + (r0      + l16) * 512 + kbase);
        short8 a1 = *(const short8*)(xb + (r0 + 16 + l16) * 512 + kbase);
#pragma unroll
        for (int c = 0; c < 4; ++c) {
            short8 b = *(const short8*)(w + (c * 16 + l16) * 512 + kbase);
            acc[0][c] = __builtin_amdgcn_mfma_f32_16x16x32_bf16(a0, b, acc[0][c], 0, 0, 0);
            acc[1][c] = __builtin_amdgcn_mfma_f32_16x16x32_bf16(a1, b, acc[1][c], 0, 0, 0);
        }
    }
    const float scale = (mat == 0) ? 0.125f : 1.0f;   // fold 1/sqrt(d_k) into Q
#pragma unroll
    for (int rg = 0; rg < 2; ++rg)
#pragma unroll
        for (int c = 0; c < 4; ++c)
#pragma unroll
            for (int r = 0; r < 4; ++r) {
                int row = r0 + rg * 16 + quad * 4 + r;   // C/D: row=(lane>>4)*4+reg
                int col = c * 16 + l16;                  //      col=lane&15
                unsigned short hv = f2bf(acc[rg][c][r] * scale);
                if (mat == 0)       qb[row * 64 + col] = hv;
                else if (mat == 1)  kb[row * 64 + col] = hv;
                else                vt[col * 8192 + row] = hv;   // V^T
            }
}

// ---------------- kernel 2: flash-style causal attention ----------------
// One wave per block, 16 Q rows per wave, K/V tiles of 32.
__global__ __launch_bounds__(64) void attn_kernel(const unsigned short* __restrict__ qb,
                                                  const unsigned short* __restrict__ kb,
                                                  const unsigned short* __restrict__ vt,
                                                  float* __restrict__ out) {
    __shared__ unsigned short lds_p[16 * 32];   // P tile, row-major [16][32]
    const int lane = threadIdx.x;
    const int l16 = lane & 15, quad = lane >> 4;
    const int qt = (int)gridDim.x - 1 - (int)blockIdx.x;   // heaviest tiles first
    const int q0 = qt * 16;

    // Q A-frags (Q pre-scaled by 1/8): lane holds Q[q0+l16][quad*8 .. +7] (+32 for frag1)
    short8 qf0 = *(const short8*)(qb + (q0 + l16) * 64 + quad * 8);
    short8 qf1 = *(const short8*)(qb + (q0 + l16) * 64 + 32 + quad * 8);

    f32x4 o[4] = {};
    float m_i[4], l_i[4];
#pragma unroll
    for (int r = 0; r < 4; ++r) { m_i[r] = -3.0e38f; l_i[r] = 0.0f; }

    const int jmax = (q0 + 15) / 32 + 1;
    for (int jt = 0; jt < jmax; ++jt) {
        const int k0 = jt * 32;
        // K B-frags: chunk c (16 K-rows), k-step s (dims 0..31 / 32..63)
        short8 kf[2][2];
#pragma unroll
        for (int c = 0; c < 2; ++c)
#pragma unroll
            for (int s = 0; s < 2; ++s)
                kf[c][s] = *(const short8*)(kb + (k0 + c * 16 + l16) * 64 + s * 32 + quad * 8);
        // V B-frags from V^T: lane holds V[k0+quad*8 .. +7][cc*16+l16] contiguously
        short8 vf[4];
#pragma unroll
        for (int cc = 0; cc < 4; ++cc)
            vf[cc] = *(const short8*)(vt + (cc * 16 + l16) * 8192 + k0 + quad * 8);

        // S = Q K^T (16x32) as two 16x16 C-frags
        f32x4 sc[2];
#pragma unroll
        for (int c = 0; c < 2; ++c) {
            f32x4 z = {};
            z     = __builtin_amdgcn_mfma_f32_16x16x32_bf16(qf0, kf[c][0], z, 0, 0, 0);
            sc[c] = __builtin_amdgcn_mfma_f32_16x16x32_bf16(qf1, kf[c][1], z, 0, 0, 0);
        }

        // causal mask + row max (rows = quad*4+r, cols = c*16+l16)
        float mcur[4];
#pragma unroll
        for (int r = 0; r < 4; ++r) {
            const int rowg = q0 + quad * 4 + r;
#pragma unroll
            for (int c = 0; c < 2; ++c) {
                const int colg = k0 + c * 16 + l16;
                if (colg > rowg) sc[c][r] = -3.0e38f;
            }
            mcur[r] = fmaxf(sc[0][r], sc[1][r]);
        }
#pragma unroll
        for (int off = 1; off < 16; off <<= 1)
#pragma unroll
            for (int r = 0; r < 4; ++r)
                mcur[r] = fmaxf(mcur[r], __shfl_xor(mcur[r], off, 64));

        float alpha[4], ls[4];
#pragma unroll
        for (int r = 0; r < 4; ++r) {
            float mn = fmaxf(m_i[r], mcur[r]);
            alpha[r] = __expf(m_i[r] - mn);
            m_i[r] = mn;
            float p0 = __expf(sc[0][r] - mn);
            float p1 = __expf(sc[1][r] - mn);
            sc[0][r] = p0; sc[1][r] = p1;
            ls[r] = p0 + p1;
        }
#pragma unroll
        for (int off = 1; off < 16; off <<= 1)
#pragma unroll
            for (int r = 0; r < 4; ++r)
                ls[r] += __shfl_xor(ls[r], off, 64);
#pragma unroll
        for (int r = 0; r < 4; ++r) l_i[r] = alpha[r] * l_i[r] + ls[r];

        // rescale O (same row mapping as S)
#pragma unroll
        for (int cc = 0; cc < 4; ++cc)
#pragma unroll
            for (int r = 0; r < 4; ++r)
                o[cc][r] *= alpha[r];

        // P: C-layout -> LDS row-major [16][32] -> A-frag
#pragma unroll
        for (int c = 0; c < 2; ++c)
#pragma unroll
            for (int r = 0; r < 4; ++r)
                lds_p[(quad * 4 + r) * 32 + c * 16 + l16] = f2bf(sc[c][r]);
        __syncthreads();
        short8 pa = *(const short8*)(lds_p + l16 * 32 + quad * 8);
        __syncthreads();

        // O += P @ V
#pragma unroll
        for (int cc = 0; cc < 4; ++cc)
            o[cc] = __builtin_amdgcn_mfma_f32_16x16x32_bf16(pa, vf[cc], o[cc], 0, 0, 0);
    }

    // epilogue: O / l_i
#pragma unroll
    for (int cc = 0; cc < 4; ++cc)
#pragma unroll
        for (int r = 0; r < 4; ++r) {
            const int rowg = q0 + quad * 4 + r;
            out[rowg * 64 + cc * 16 + l16] = o[cc][r] / l_i[r];
        }
}

extern "C" void kernel_launch(void* const* d_in, const int* in_sizes, int n_in,
                              void* d_out, int out_size, void* d_ws, size_t ws_size,
                              hipStream_t stream) {
    const float* x  = (const float*)d_in[0];
    const float* wq = (const float*)d_in[1];
    const float* wk = (const float*)d_in[2];
    const float* wv = (const float*)d_in[3];
    float* out = (float*)d_out;

    char* ws = (char*)d_ws;
    // ws layout (bytes):
    unsigned short* xb = (unsigned short*)(ws);              // 8192*512*2 = 8,388,608
    unsigned short* wb = (unsigned short*)(ws + 8388608);    // 3*64*512*2 =   196,608
    unsigned short* qb = (unsigned short*)(ws + 8585216);    // 8192*64*2  = 1,048,576
    unsigned short* kb = (unsigned short*)(ws + 9633792);    // 1,048,576
    unsigned short* vt = (unsigned short*)(ws + 10682368);   // 1,048,576  (V^T [64][8192])

    cast_x_kernel<<<4096, 256, 0, stream>>>(x, xb, (8192 * 512) / 4);
    cast_w_kernel<<<dim3(32, 3), 256, 0, stream>>>(wq, wk, wv, wb);
    proj_kernel<<<dim3(256, 3), 64, 0, stream>>>(xb, wb, qb, kb, vt);
    attn_kernel<<<512, 64, 0, stream>>>(qb, kb, vt, out);
}